// Round 7
// baseline (6908.168 us; speedup 1.0000x reference)
//
#include <hip/hip_runtime.h>
#include <hip/hip_bf16.h>

#define CB 256      // batch
#define CN 256      // nodes
#define CK 3        // children per node
#define CE 256      // embedding dim
#define CH 256      // hidden dim
#define CG_ 1536    // gates = 6*CH (i, o, u, f0, f1, f2)

// ---------------------------------------------------------------------------
// One tree step per launch (no cross-block sync needed). Block (bi,hi) owns a
// (16 batch x 16 hidden) patch; computes its 6 gate columns via a K=1024 GEMM
// over [x | masked child h] staged in LDS, then the LSTM cell update.
// ALL dtypes fp32 (inputs verified fp32 by the round-6 NaN probe; OUTPUT is
// fp32 per the documented ABI: reference output dtype fp32 -> float*).
// ---------------------------------------------------------------------------
__global__ __launch_bounds__(512) void tree_step(
    const int* __restrict__ node_ids,          // [B][N]
    const int* __restrict__ children,          // [B][N][K]
    const float* __restrict__ emb,             // [V][E]
    const float* __restrict__ Wx_w,            // [E][G]
    const float* __restrict__ Wx_b,            // [G]
    const float* __restrict__ Uh_w,            // [K*H][G]
    const float* __restrict__ Uh_b,            // [K][G]
    float* __restrict__ h_s,                   // [N][B][H] f32 history
    float* __restrict__ c_s,                   // [N][B][H] f32 history
    float* __restrict__ out,                   // [B][H] f32  (per ABI docs)
    const int t)
{
    const int tid = threadIdx.x;

    const int xcd  = blockIdx.x & 7;
    const int bidx = blockIdx.x >> 3;          // 0..31
    const int hi   = xcd * 2 + (bidx & 1);     // 0..15
    const int bi   = bidx >> 1;                // 0..15
    const int b0   = bi * 16;
    const int hh0  = hi * 16;

    const int tt   = tid >> 6;                 // 0..7  K-eighth
    const int lane = tid & 63;
    const int bq   = lane >> 4;                // 0..3  batch quad
    const int jj   = lane & 15;                // 0..15 hh col

    __shared__ float xh[16][1025];             // [lb][ x(256) | h_k0 | h_k1 | h_k2 ]
    __shared__ float gred[8][16][6][16];       // [tt][bb][q][jj] partials
    __shared__ int   nid[16];
    __shared__ float msk[16][3];
    __shared__ int   cix[16][3];

    if (tid < 16) nid[tid] = node_ids[(size_t)(b0 + tid) * CN + t];
    if (tid < 48) {
        int lb = tid / 3, k = tid - lb * 3;
        int raw = children[((size_t)(b0 + lb) * CN + t) * CK + k];
        int v = raw < t;
        msk[lb][k] = v ? 1.0f : 0.0f;
        cix[lb][k] = v ? raw : 0;
    }
    __syncthreads();

    // stage [x | masked child h]: 16 rows x 1024 cols, 32 elems per thread
    for (int i = 0; i < 32; ++i) {
        int id2 = tid + (i << 9);
        int lb  = id2 >> 10;                   // 0..15
        int col = id2 & 1023;
        float v;
        if (col < CE) {
            v = emb[(size_t)nid[lb] * CE + col];
        } else {
            int k  = (col - CE) >> 8;          // 0..2
            int hc = col & 255;
            v = 0.0f;
            if (msk[lb][k] != 0.0f)
                v = h_s[((size_t)cix[lb][k] * CB + (b0 + lb)) * CH + hc];
        }
        xh[lb][col] = v;
    }
    __syncthreads();

    // GEMM: 128 virtual-K rows per tt; 4 batches x 6 gates per thread
    float acc[4][6] = {};
    {
        const float* w0p = (tt < 2)
            ? (Wx_w + (size_t)(tt * 128) * CG_ + (hh0 + jj))
            : (Uh_w + (size_t)(tt * 128 - 256) * CG_ + (hh0 + jj));
        const int colbase = tt * 128;
        #pragma unroll 4
        for (int kl = 0; kl < 128; ++kl) {
            const float* wr = w0p + (size_t)kl * CG_;
            float w0 = wr[0],    w1 = wr[256],  w2 = wr[512];
            float w3 = wr[768],  w4 = wr[1024], w5 = wr[1280];
            int col = colbase + kl;
            #pragma unroll
            for (int r = 0; r < 4; ++r) {
                float hv = xh[bq + 4 * r][col];
                acc[r][0] += hv * w0; acc[r][1] += hv * w1; acc[r][2] += hv * w2;
                acc[r][3] += hv * w3; acc[r][4] += hv * w4; acc[r][5] += hv * w5;
            }
        }
    }
    #pragma unroll
    for (int r = 0; r < 4; ++r)
        #pragma unroll
        for (int q = 0; q < 6; ++q)
            gred[tt][bq + 4 * r][q][jj] = acc[r][q];
    __syncthreads();

    if (tid < 256) {
        const int bb = tid >> 4, j2 = tid & 15;
        const int b = b0 + bb, hh = hh0 + j2;
        float g[6];
        #pragma unroll
        for (int q = 0; q < 6; ++q) {
            float s = 0.0f;
            #pragma unroll
            for (int k = 0; k < 8; ++k) s += gred[k][bb][q][j2];
            g[q] = s;
        }
        const float m0 = msk[bb][0], m1 = msk[bb][1], m2 = msk[bb][2];
        #pragma unroll
        for (int q = 0; q < 6; ++q) {
            int gc = q * CH + hh;
            g[q] += Wx_b[gc] + m0 * Uh_b[gc] + m1 * Uh_b[CG_ + gc]
                             + m2 * Uh_b[2 * CG_ + gc];
        }
        float ig = 1.0f / (1.0f + expf(-g[0]));
        float og = 1.0f / (1.0f + expf(-g[1]));
        float ug = tanhf(g[2]);
        float c = ig * ug;
        if (m0 != 0.0f) c += (1.0f / (1.0f + expf(-g[3]))) * c_s[((size_t)cix[bb][0] * CB + b) * CH + hh];
        if (m1 != 0.0f) c += (1.0f / (1.0f + expf(-g[4]))) * c_s[((size_t)cix[bb][1] * CB + b) * CH + hh];
        if (m2 != 0.0f) c += (1.0f / (1.0f + expf(-g[5]))) * c_s[((size_t)cix[bb][2] * CB + b) * CH + hh];
        float h = og * tanhf(c);
        h_s[((size_t)t * CB + b) * CH + hh] = h;
        c_s[((size_t)t * CB + b) * CH + hh] = c;
        if (t == CN - 1) out[(size_t)b * CH + hh] = h;
    }
}

// Diagnostic: write a constant to d_out so absmax reveals which check failed.
__global__ void ws_report(float* out, int n, float val) {
    int i = blockIdx.x * blockDim.x + threadIdx.x;
    if (i < n) out[i] = val;
}

// ---------------------------------------------------------------------------
extern "C" void kernel_launch(void* const* d_in, const int* in_sizes, int n_in,
                              void* d_out, int out_size, void* d_ws, size_t ws_size,
                              hipStream_t stream) {
    float* outp = (float*)d_out;

    // ABI probe (host-side, free): verify input count and flat element counts.
    const int expect_sizes[7] = {65536, 196608, 8192000, 393216, 1536, 1179648, 4608};
    int bad = -1;
    if (n_in != 7) bad = 7;
    else for (int i = 0; i < 7; ++i) if (in_sizes[i] != expect_sizes[i]) { bad = i; break; }
    if (bad >= 0) {
        ws_report<<<(out_size + 255) / 256, 256, 0, stream>>>(outp, out_size, 1000.0f + bad);
        return;
    }

    const int*   node_ids = (const int*)d_in[0];
    const int*   children = (const int*)d_in[1];
    const float* emb      = (const float*)d_in[2];
    const float* Wx_w     = (const float*)d_in[3];
    const float* Wx_b     = (const float*)d_in[4];
    const float* Uh_w     = (const float*)d_in[5];
    const float* Uh_b     = (const float*)d_in[6];

    const size_t need = (size_t)CN * CB * CH * 4 * 2;   // h_s + c_s, 128 MB
    if (ws_size < need) {
        ws_report<<<(out_size + 255) / 256, 256, 0, stream>>>(
            outp, out_size, (float)(ws_size >> 20));
        return;
    }
    float* h_s = (float*)d_ws;
    float* c_s = (float*)((char*)d_ws + need / 2);

    for (int t = 0; t < CN; ++t) {
        tree_step<<<dim3(256), dim3(512), 0, stream>>>(
            node_ids, children, emb, Wx_w, Wx_b, Uh_w, Uh_b,
            h_s, c_s, outp, t);
    }
}